// Round 11
// baseline (52.752 us; speedup 1.0000x reference)
//
#include <hip/hip_runtime.h>
#include <hip/hip_fp16.h>

#define D_DIM 4096
#define H_DIM 4096
#define SLP 80   // padded LDS stride (halves): 160B = 16B-aligned, rows 2-way = free

__device__ __forceinline__ float fast_sigmoid(float a) {
    return __builtin_amdgcn_rcpf(1.0f + __expf(-a));
}

// ---------------- Kernel A: split-row scans -> S fp16 (32 MB ws) ----------
// Block = 512 thr = 8 waves = 4 rows x 2 half-row waves; grid 1024.
// Each wave scans 2048 cols (4 tiles of 512): local exclusive values kept in
// 32 regs (pre-base), half-0 total exchanged via LDS, then base+sigmoid+store.
// 8192 total waves -> ~24-32 waves/CU (vs 16 before), serial chain halved.
__global__ __launch_bounds__(512, 6) void nade_scan_kernel(
    const float* __restrict__ x,
    const float* __restrict__ w,
    const float* __restrict__ c,
    __half* __restrict__ S)
{
    __shared__ float tot0[4];

    const int tid  = threadIdx.x;
    const int wv   = tid >> 6;
    const int lane = tid & 63;
    const int rl   = wv >> 1;      // local row 0..3
    const int half = wv & 1;       // which 2048-col half
    const int h    = blockIdx.x * 4 + rl;

    const float* wrow = w + (size_t)h * D_DIM + half * 2048 + 8 * lane;
    const float* xcol = x + half * 2048 + 8 * lane;
    __half*      srow = S + (size_t)h * D_DIM + half * 2048 + 8 * lane;

    float l[32];                   // local exclusive pre-base values (regs)
    float carry = 0.0f;

    float4 wc0 = *reinterpret_cast<const float4*>(wrow);
    float4 wc1 = *reinterpret_cast<const float4*>(wrow + 4);

    #pragma unroll
    for (int t = 0; t < 4; ++t) {
        float4 wn0, wn1;
        if (t < 3) {
            wn0 = *reinterpret_cast<const float4*>(wrow + (t + 1) * 512);
            wn1 = *reinterpret_cast<const float4*>(wrow + (t + 1) * 512 + 4);
        }
        float4 x0 = *reinterpret_cast<const float4*>(xcol + t * 512);
        float4 x1 = *reinterpret_cast<const float4*>(xcol + t * 512 + 4);
        float p0 = wc0.x * x0.x, p1 = wc0.y * x0.y, p2 = wc0.z * x0.z, p3 = wc0.w * x0.w;
        float p4 = wc1.x * x1.x, p5 = wc1.y * x1.y, p6 = wc1.z * x1.z, p7 = wc1.w * x1.w;
        float s8 = ((p0 + p1) + (p2 + p3)) + ((p4 + p5) + (p6 + p7));
        float incl = s8;
        #pragma unroll
        for (int off = 1; off < 64; off <<= 1) {
            float tv = __shfl_up(incl, off, 64);
            incl += (lane >= off) ? tv : 0.0f;
        }
        float a = carry + incl - s8;    // exclusive prefix within this half
        l[8*t+0] = a; a += p0;
        l[8*t+1] = a; a += p1;
        l[8*t+2] = a; a += p2;
        l[8*t+3] = a; a += p3;
        l[8*t+4] = a; a += p4;
        l[8*t+5] = a; a += p5;
        l[8*t+6] = a; a += p6;
        l[8*t+7] = a;
        carry += __shfl(incl, 63, 64);
        wc0 = wn0; wc1 = wn1;
    }

    if (half == 0 && lane == 63) tot0[rl] = carry;
    __syncthreads();

    const float base = c[h] + (half ? tot0[rl] : 0.0f);

    #pragma unroll
    for (int t = 0; t < 4; ++t) {
        union { __half2 h2[4]; uint4 u; } P;
        #pragma unroll
        for (int j = 0; j < 4; ++j)
            P.h2[j] = __floats2half2_rn(fast_sigmoid(l[8*t+2*j]   + base),
                                        fast_sigmoid(l[8*t+2*j+1] + base));
        *reinterpret_cast<uint4*>(srow + t * 512) = P.u;
    }
}

// ---------------- Kernel B: part[ht][i] = sum_{h in tile} v[i,h]*S[h,i] ----
// grid 2048 (64 i-tiles x 32 h-tiles) x 256 thr; LDS 21 KB -> 7 blocks/CU.
// S tile padded to stride 80 halves: staging writes 2-way (free), reads 2-way.
__global__ __launch_bounds__(256, 8) void nade_vdot_kernel(
    const float* __restrict__ v,
    const __half* __restrict__ S,
    float* __restrict__ part)
{
    __shared__ __half Sl[128][SLP];   // 20 KB
    __shared__ float red[4][64];

    const int tid = threadIdx.x;
    const int it  = blockIdx.x & 63;
    const int ht  = blockIdx.x >> 6;
    const int i0  = it * 64;
    const int h0  = ht * 128;

    // stage S tile: 128 rows x 128B
    {
        const int r  = tid >> 3;       // 32 rows per pass
        const int c8 = tid & 7;        // 16B chunk in row
        #pragma unroll
        for (int p = 0; p < 4; ++p) {
            const int hh = p * 32 + r;
            uint4 d = *reinterpret_cast<const uint4*>(
                S + (size_t)(h0 + hh) * D_DIM + i0 + c8 * 8);
            *reinterpret_cast<uint4*>(&Sl[hh][c8 * 8]) = d;
        }
    }
    __syncthreads();

    const int il = tid & 63;           // i within tile
    const int q  = tid >> 6;           // wave = 32-h subrange
    const float* vp = v + (size_t)(i0 + il) * H_DIM + h0 + q * 32;

    float4 va[8];
    #pragma unroll
    for (int k = 0; k < 8; ++k)
        va[k] = *reinterpret_cast<const float4*>(vp + 4 * k);

    float acc = 0.0f;
    #pragma unroll
    for (int k = 0; k < 8; ++k) {
        const int hb = q * 32 + 4 * k;
        acc += va[k].x * __half2float(Sl[hb + 0][il])
             + va[k].y * __half2float(Sl[hb + 1][il])
             + va[k].z * __half2float(Sl[hb + 2][il])
             + va[k].w * __half2float(Sl[hb + 3][il]);
    }
    red[q][il] = acc;
    __syncthreads();
    if (q == 0)
        part[(size_t)ht * D_DIM + i0 + il] =
            red[0][il] + red[1][il] + red[2][il] + red[3][il];
}

// ---------------- Kernel C: out = sigmoid(b + sum_32 part) ----------------
__global__ __launch_bounds__(256, 8) void nade_out_kernel(
    const float* __restrict__ part,
    const float* __restrict__ b,
    float* __restrict__ out)
{
    const int i = blockIdx.x * 256 + threadIdx.x;
    float t = b[i];
    #pragma unroll
    for (int s = 0; s < 32; ++s)
        t += part[(size_t)s * D_DIM + i];
    out[i] = fast_sigmoid(t);
}

// ---------------- Fallback (ws too small): fused atomic ----------------
__global__ __launch_bounds__(1024, 1) void nade_fused_atomic(
    const float* __restrict__ x,
    const float* __restrict__ w,
    const float* __restrict__ v,
    const float* __restrict__ c,
    float* __restrict__ logits)
{
    __shared__ __half S[16][D_DIM];   // 128 KB

    const int tid  = threadIdx.x;
    const int wv   = tid >> 6;
    const int lane = tid & 63;
    const int h0   = blockIdx.x * 16;

    const float* wrow = w + (size_t)(h0 + wv) * D_DIM + 8 * lane;
    float carry = c[h0 + wv];
    #pragma unroll
    for (int t = 0; t < 8; ++t) {
        float4 w0 = *reinterpret_cast<const float4*>(wrow + t * 512);
        float4 w1 = *reinterpret_cast<const float4*>(wrow + t * 512 + 4);
        float4 x0 = *reinterpret_cast<const float4*>(x + t * 512 + 8 * lane);
        float4 x1 = *reinterpret_cast<const float4*>(x + t * 512 + 8 * lane + 4);
        float p0 = w0.x * x0.x, p1 = w0.y * x0.y, p2 = w0.z * x0.z, p3 = w0.w * x0.w;
        float p4 = w1.x * x1.x, p5 = w1.y * x1.y, p6 = w1.z * x1.z, p7 = w1.w * x1.w;
        float s8 = ((p0 + p1) + (p2 + p3)) + ((p4 + p5) + (p6 + p7));
        float incl = s8;
        #pragma unroll
        for (int off = 1; off < 64; off <<= 1) {
            float tv = __shfl_up(incl, off, 64);
            incl += (lane >= off) ? tv : 0.0f;
        }
        float tot = __shfl(incl, 63, 64);
        float a = carry + incl - s8;
        float sg0 = fast_sigmoid(a); a += p0;
        float sg1 = fast_sigmoid(a); a += p1;
        float sg2 = fast_sigmoid(a); a += p2;
        float sg3 = fast_sigmoid(a); a += p3;
        float sg4 = fast_sigmoid(a); a += p4;
        float sg5 = fast_sigmoid(a); a += p5;
        float sg6 = fast_sigmoid(a); a += p6;
        float sg7 = fast_sigmoid(a);
        carry += tot;
        union { __half2 h2[4]; uint4 u; } P;
        P.h2[0] = __floats2half2_rn(sg0, sg1);
        P.h2[1] = __floats2half2_rn(sg2, sg3);
        P.h2[2] = __floats2half2_rn(sg4, sg5);
        P.h2[3] = __floats2half2_rn(sg6, sg7);
        *reinterpret_cast<uint4*>(&S[wv][t * 512 + 8 * lane]) = P.u;
    }
    __syncthreads();

    const int i0 = 4 * tid;
    float acc[4] = {0.f, 0.f, 0.f, 0.f};
    #pragma unroll
    for (int r = 0; r < 4; ++r) {
        const float* vp = v + (size_t)(i0 + r) * H_DIM + h0;
        float4 q0 = *reinterpret_cast<const float4*>(vp);
        float4 q1 = *reinterpret_cast<const float4*>(vp + 4);
        float4 q2 = *reinterpret_cast<const float4*>(vp + 8);
        float4 q3 = *reinterpret_cast<const float4*>(vp + 12);
        acc[r] = q0.x * __half2float(S[0][i0 + r])  + q0.y * __half2float(S[1][i0 + r])
               + q0.z * __half2float(S[2][i0 + r])  + q0.w * __half2float(S[3][i0 + r])
               + q1.x * __half2float(S[4][i0 + r])  + q1.y * __half2float(S[5][i0 + r])
               + q1.z * __half2float(S[6][i0 + r])  + q1.w * __half2float(S[7][i0 + r])
               + q2.x * __half2float(S[8][i0 + r])  + q2.y * __half2float(S[9][i0 + r])
               + q2.z * __half2float(S[10][i0 + r]) + q2.w * __half2float(S[11][i0 + r])
               + q3.x * __half2float(S[12][i0 + r]) + q3.y * __half2float(S[13][i0 + r])
               + q3.z * __half2float(S[14][i0 + r]) + q3.w * __half2float(S[15][i0 + r]);
    }
    #pragma unroll
    for (int r = 0; r < 4; ++r) atomicAdd(&logits[i0 + r], acc[r]);
}

__global__ __launch_bounds__(256, 1) void nade_final_atomic(
    const float* __restrict__ logits,
    const float* __restrict__ b,
    float* __restrict__ out)
{
    const int i = blockIdx.x * 256 + threadIdx.x;
    out[i] = fast_sigmoid(logits[i] + b[i]);
}

extern "C" void kernel_launch(void* const* d_in, const int* in_sizes, int n_in,
                              void* d_out, int out_size, void* d_ws, size_t ws_size,
                              hipStream_t stream)
{
    const float* x = (const float*)d_in[0];
    const float* w = (const float*)d_in[1];
    const float* b = (const float*)d_in[2];
    const float* v = (const float*)d_in[3];
    const float* c = (const float*)d_in[4];
    float* out = (float*)d_out;

    const size_t s_bytes    = (size_t)H_DIM * D_DIM * sizeof(__half);   // 32 MB
    const size_t part_bytes = (size_t)32 * D_DIM * sizeof(float);       // 512 KB

    if (ws_size >= s_bytes + part_bytes) {
        __half* S    = (__half*)d_ws;
        float*  part = (float*)((char*)d_ws + s_bytes);
        nade_scan_kernel<<<H_DIM / 4, 512, 0, stream>>>(x, w, c, S);
        nade_vdot_kernel<<<64 * 32, 256, 0, stream>>>(v, S, part);
        nade_out_kernel<<<D_DIM / 256, 256, 0, stream>>>(part, b, out);
    } else {
        float* logits = (float*)d_ws;
        hipMemsetAsync(logits, 0, D_DIM * sizeof(float), stream);
        nade_fused_atomic<<<H_DIM / 16, 1024, 0, stream>>>(x, w, v, c, logits);
        nade_final_atomic<<<D_DIM / 256, 256, 0, stream>>>(logits, b, out);
    }
}

// Round 12
// 51.953 us; speedup vs baseline: 1.0154x; 1.0154x over previous
//
#include <hip/hip_runtime.h>
#include <hip/hip_fp16.h>

#define D_DIM 4096
#define H_DIM 4096
#define SLP 80   // padded LDS stride (halves): 160B -> staging rows 2-way (free)

__device__ __forceinline__ float fast_sigmoid(float a) {
    return __builtin_amdgcn_rcpf(1.0f + __expf(-a));
}

// ---------------- Kernel A: row scans -> S fp16 (32 MB ws) ----------------
// grid 1024 x 256 thr (4 waves); wave owns row h = blockIdx.x*4 + (tid>>6).
// 4-deep ring prefetch of w (slots A..D, 32 VGPR): ring WAR deps anchor the
// loads in program order -> compiler emits incremental vmcnt, 128B/wave in
// flight instead of R10's 32B. No asm pins (those force full drains).
__global__ __launch_bounds__(256, 4) void nade_scan_kernel(
    const float* __restrict__ x,
    const float* __restrict__ w,
    const float* __restrict__ c,
    __half* __restrict__ S)
{
    const int tid  = threadIdx.x;
    const int lane = tid & 63;
    const int h    = blockIdx.x * 4 + (tid >> 6);

    const float* wrow = w + (size_t)h * D_DIM + 8 * lane;
    __half*      srow = S + (size_t)h * D_DIM + 8 * lane;
    float carry = c[h];

    float4 wA0 = *reinterpret_cast<const float4*>(wrow + 0 * 512);
    float4 wA1 = *reinterpret_cast<const float4*>(wrow + 0 * 512 + 4);
    float4 wB0 = *reinterpret_cast<const float4*>(wrow + 1 * 512);
    float4 wB1 = *reinterpret_cast<const float4*>(wrow + 1 * 512 + 4);
    float4 wC0 = *reinterpret_cast<const float4*>(wrow + 2 * 512);
    float4 wC1 = *reinterpret_cast<const float4*>(wrow + 2 * 512 + 4);
    float4 wD0 = *reinterpret_cast<const float4*>(wrow + 3 * 512);
    float4 wD1 = *reinterpret_cast<const float4*>(wrow + 3 * 512 + 4);

    float4 xc0 = *reinterpret_cast<const float4*>(x + 8 * lane);
    float4 xc1 = *reinterpret_cast<const float4*>(x + 8 * lane + 4);

    auto tile = [&](int t, float4& WS0, float4& WS1) {
        float4 u0 = WS0, u1 = WS1;            // consume slot (waits this slot only)
        if (t + 4 < 8) {                      // refill freed slot (keeps 4-deep)
            WS0 = *reinterpret_cast<const float4*>(wrow + (t + 4) * 512);
            WS1 = *reinterpret_cast<const float4*>(wrow + (t + 4) * 512 + 4);
        }
        float4 xn0, xn1;
        if (t < 7) {
            xn0 = *reinterpret_cast<const float4*>(x + (t + 1) * 512 + 8 * lane);
            xn1 = *reinterpret_cast<const float4*>(x + (t + 1) * 512 + 8 * lane + 4);
        }
        float p0 = u0.x * xc0.x, p1 = u0.y * xc0.y, p2 = u0.z * xc0.z, p3 = u0.w * xc0.w;
        float p4 = u1.x * xc1.x, p5 = u1.y * xc1.y, p6 = u1.z * xc1.z, p7 = u1.w * xc1.w;
        float s8 = ((p0 + p1) + (p2 + p3)) + ((p4 + p5) + (p6 + p7));
        float incl = s8;
        #pragma unroll
        for (int off = 1; off < 64; off <<= 1) {
            float tv = __shfl_up(incl, off, 64);
            incl += (lane >= off) ? tv : 0.0f;
        }
        float tot = __shfl(incl, 63, 64);
        float a = carry + incl - s8;          // exclusive prefix + carry
        float sg0 = fast_sigmoid(a); a += p0;
        float sg1 = fast_sigmoid(a); a += p1;
        float sg2 = fast_sigmoid(a); a += p2;
        float sg3 = fast_sigmoid(a); a += p3;
        float sg4 = fast_sigmoid(a); a += p4;
        float sg5 = fast_sigmoid(a); a += p5;
        float sg6 = fast_sigmoid(a); a += p6;
        float sg7 = fast_sigmoid(a);
        carry += tot;

        union { __half2 h2[4]; uint4 u; } P;
        P.h2[0] = __floats2half2_rn(sg0, sg1);
        P.h2[1] = __floats2half2_rn(sg2, sg3);
        P.h2[2] = __floats2half2_rn(sg4, sg5);
        P.h2[3] = __floats2half2_rn(sg6, sg7);
        *reinterpret_cast<uint4*>(srow + t * 512) = P.u;

        if (t < 7) { xc0 = xn0; xc1 = xn1; }
    };

    tile(0, wA0, wA1); tile(1, wB0, wB1); tile(2, wC0, wC1); tile(3, wD0, wD1);
    tile(4, wA0, wA1); tile(5, wB0, wB1); tile(6, wC0, wC1); tile(7, wD0, wD1);
}

// ---------------- Kernel B: part[ht][i] = sum_{h in tile} v[i,h]*S[h,i] ----
// grid 2048 (64 i-tiles x 32 h-tiles) x 256 thr. S tile padded to stride 80
// halves: staging writes 2-way (free, was 8-way), reads 2-way (free).
__global__ __launch_bounds__(256, 8) void nade_vdot_kernel(
    const float* __restrict__ v,
    const __half* __restrict__ S,
    float* __restrict__ part)
{
    __shared__ __half Sl[128][SLP];   // 20 KB
    __shared__ float red[4][64];

    const int tid = threadIdx.x;
    const int it  = blockIdx.x & 63;
    const int ht  = blockIdx.x >> 6;
    const int i0  = it * 64;
    const int h0  = ht * 128;

    // stage S tile: 128 rows x 128B
    {
        const int r  = tid >> 3;       // 32 rows per pass
        const int c8 = tid & 7;        // 16B chunk in row
        #pragma unroll
        for (int p = 0; p < 4; ++p) {
            const int hh = p * 32 + r;
            uint4 d = *reinterpret_cast<const uint4*>(
                S + (size_t)(h0 + hh) * D_DIM + i0 + c8 * 8);
            *reinterpret_cast<uint4*>(&Sl[hh][c8 * 8]) = d;
        }
    }
    __syncthreads();

    const int il = tid & 63;           // i within tile
    const int q  = tid >> 6;           // wave = 32-h subrange
    const float* vp = v + (size_t)(i0 + il) * H_DIM + h0 + q * 32;

    float4 va[8];
    #pragma unroll
    for (int k = 0; k < 8; ++k)
        va[k] = *reinterpret_cast<const float4*>(vp + 4 * k);

    float acc = 0.0f;
    #pragma unroll
    for (int k = 0; k < 8; ++k) {
        const int hb = q * 32 + 4 * k;
        acc += va[k].x * __half2float(Sl[hb + 0][il])
             + va[k].y * __half2float(Sl[hb + 1][il])
             + va[k].z * __half2float(Sl[hb + 2][il])
             + va[k].w * __half2float(Sl[hb + 3][il]);
    }
    red[q][il] = acc;
    __syncthreads();
    if (q == 0)
        part[(size_t)ht * D_DIM + i0 + il] =
            red[0][il] + red[1][il] + red[2][il] + red[3][il];
}

// ---------------- Kernel C: out = sigmoid(b + sum_32 part) ----------------
__global__ __launch_bounds__(256, 8) void nade_out_kernel(
    const float* __restrict__ part,
    const float* __restrict__ b,
    float* __restrict__ out)
{
    const int i = blockIdx.x * 256 + threadIdx.x;
    float t = b[i];
    #pragma unroll
    for (int s = 0; s < 32; ++s)
        t += part[(size_t)s * D_DIM + i];
    out[i] = fast_sigmoid(t);
}

// ---------------- Fallback (ws too small): fused atomic ----------------
__global__ __launch_bounds__(1024, 1) void nade_fused_atomic(
    const float* __restrict__ x,
    const float* __restrict__ w,
    const float* __restrict__ v,
    const float* __restrict__ c,
    float* __restrict__ logits)
{
    __shared__ __half S[16][D_DIM];   // 128 KB

    const int tid  = threadIdx.x;
    const int wv   = tid >> 6;
    const int lane = tid & 63;
    const int h0   = blockIdx.x * 16;

    const float* wrow = w + (size_t)(h0 + wv) * D_DIM + 8 * lane;
    float carry = c[h0 + wv];
    #pragma unroll
    for (int t = 0; t < 8; ++t) {
        float4 w0 = *reinterpret_cast<const float4*>(wrow + t * 512);
        float4 w1 = *reinterpret_cast<const float4*>(wrow + t * 512 + 4);
        float4 x0 = *reinterpret_cast<const float4*>(x + t * 512 + 8 * lane);
        float4 x1 = *reinterpret_cast<const float4*>(x + t * 512 + 8 * lane + 4);
        float p0 = w0.x * x0.x, p1 = w0.y * x0.y, p2 = w0.z * x0.z, p3 = w0.w * x0.w;
        float p4 = w1.x * x1.x, p5 = w1.y * x1.y, p6 = w1.z * x1.z, p7 = w1.w * x1.w;
        float s8 = ((p0 + p1) + (p2 + p3)) + ((p4 + p5) + (p6 + p7));
        float incl = s8;
        #pragma unroll
        for (int off = 1; off < 64; off <<= 1) {
            float tv = __shfl_up(incl, off, 64);
            incl += (lane >= off) ? tv : 0.0f;
        }
        float tot = __shfl(incl, 63, 64);
        float a = carry + incl - s8;
        float sg0 = fast_sigmoid(a); a += p0;
        float sg1 = fast_sigmoid(a); a += p1;
        float sg2 = fast_sigmoid(a); a += p2;
        float sg3 = fast_sigmoid(a); a += p3;
        float sg4 = fast_sigmoid(a); a += p4;
        float sg5 = fast_sigmoid(a); a += p5;
        float sg6 = fast_sigmoid(a); a += p6;
        float sg7 = fast_sigmoid(a);
        carry += tot;
        union { __half2 h2[4]; uint4 u; } P;
        P.h2[0] = __floats2half2_rn(sg0, sg1);
        P.h2[1] = __floats2half2_rn(sg2, sg3);
        P.h2[2] = __floats2half2_rn(sg4, sg5);
        P.h2[3] = __floats2half2_rn(sg6, sg7);
        *reinterpret_cast<uint4*>(&S[wv][t * 512 + 8 * lane]) = P.u;
    }
    __syncthreads();

    const int i0 = 4 * tid;
    float acc[4] = {0.f, 0.f, 0.f, 0.f};
    #pragma unroll
    for (int r = 0; r < 4; ++r) {
        const float* vp = v + (size_t)(i0 + r) * H_DIM + h0;
        float4 q0 = *reinterpret_cast<const float4*>(vp);
        float4 q1 = *reinterpret_cast<const float4*>(vp + 4);
        float4 q2 = *reinterpret_cast<const float4*>(vp + 8);
        float4 q3 = *reinterpret_cast<const float4*>(vp + 12);
        acc[r] = q0.x * __half2float(S[0][i0 + r])  + q0.y * __half2float(S[1][i0 + r])
               + q0.z * __half2float(S[2][i0 + r])  + q0.w * __half2float(S[3][i0 + r])
               + q1.x * __half2float(S[4][i0 + r])  + q1.y * __half2float(S[5][i0 + r])
               + q1.z * __half2float(S[6][i0 + r])  + q1.w * __half2float(S[7][i0 + r])
               + q2.x * __half2float(S[8][i0 + r])  + q2.y * __half2float(S[9][i0 + r])
               + q2.z * __half2float(S[10][i0 + r]) + q2.w * __half2float(S[11][i0 + r])
               + q3.x * __half2float(S[12][i0 + r]) + q3.y * __half2float(S[13][i0 + r])
               + q3.z * __half2float(S[14][i0 + r]) + q3.w * __half2float(S[15][i0 + r]);
    }
    #pragma unroll
    for (int r = 0; r < 4; ++r) atomicAdd(&logits[i0 + r], acc[r]);
}

__global__ __launch_bounds__(256, 1) void nade_final_atomic(
    const float* __restrict__ logits,
    const float* __restrict__ b,
    float* __restrict__ out)
{
    const int i = blockIdx.x * 256 + threadIdx.x;
    out[i] = fast_sigmoid(logits[i] + b[i]);
}

extern "C" void kernel_launch(void* const* d_in, const int* in_sizes, int n_in,
                              void* d_out, int out_size, void* d_ws, size_t ws_size,
                              hipStream_t stream)
{
    const float* x = (const float*)d_in[0];
    const float* w = (const float*)d_in[1];
    const float* b = (const float*)d_in[2];
    const float* v = (const float*)d_in[3];
    const float* c = (const float*)d_in[4];
    float* out = (float*)d_out;

    const size_t s_bytes    = (size_t)H_DIM * D_DIM * sizeof(__half);   // 32 MB
    const size_t part_bytes = (size_t)32 * D_DIM * sizeof(float);       // 512 KB

    if (ws_size >= s_bytes + part_bytes) {
        __half* S    = (__half*)d_ws;
        float*  part = (float*)((char*)d_ws + s_bytes);
        nade_scan_kernel<<<H_DIM / 4, 256, 0, stream>>>(x, w, c, S);
        nade_vdot_kernel<<<64 * 32, 256, 0, stream>>>(v, S, part);
        nade_out_kernel<<<D_DIM / 256, 256, 0, stream>>>(part, b, out);
    } else {
        float* logits = (float*)d_ws;
        hipMemsetAsync(logits, 0, D_DIM * sizeof(float), stream);
        nade_fused_atomic<<<H_DIM / 16, 1024, 0, stream>>>(x, w, v, c, logits);
        nade_final_atomic<<<D_DIM / 256, 256, 0, stream>>>(logits, b, out);
    }
}

// Round 13
// 44.642 us; speedup vs baseline: 1.1817x; 1.1638x over previous
//
#include <hip/hip_runtime.h>
#include <hip/hip_fp16.h>

#define D_DIM 4096
#define H_DIM 4096

__device__ __forceinline__ float fast_sigmoid(float a) {
    return __builtin_amdgcn_rcpf(1.0f + __expf(-a));
}

// ---------------- Kernel A: quarter-split row scans -> S fp16 ----------------
// grid 4096 (1 block per row) x 256 thr (4 waves). Wave q owns cols
// [q*1024, q*1024+1024) = 2 tiles of 512. Local exclusive values in 16 regs,
// quarter totals via 16B LDS + one barrier, then base+sigmoid+store.
// 8 blocks/CU (tiny LDS, ~50 VGPR) -> 32 waves/CU; serial chain 8->2 tiles.
__global__ __launch_bounds__(256, 8) void nade_scan_kernel(
    const float* __restrict__ x,
    const float* __restrict__ w,
    const float* __restrict__ c,
    __half* __restrict__ S)
{
    __shared__ float qtot[4];

    const int tid  = threadIdx.x;
    const int q    = tid >> 6;          // quarter 0..3
    const int lane = tid & 63;
    const int h    = blockIdx.x;
    const int col0 = q * 1024 + 8 * lane;

    const float* wp = w + (size_t)h * D_DIM + col0;
    const float* xp = x + col0;

    // issue both tiles' w loads up front (independent -> 2-deep in flight)
    float4 w00 = *reinterpret_cast<const float4*>(wp);
    float4 w01 = *reinterpret_cast<const float4*>(wp + 4);
    float4 w10 = *reinterpret_cast<const float4*>(wp + 512);
    float4 w11 = *reinterpret_cast<const float4*>(wp + 512 + 4);
    float4 x00 = *reinterpret_cast<const float4*>(xp);
    float4 x01 = *reinterpret_cast<const float4*>(xp + 4);
    float4 x10 = *reinterpret_cast<const float4*>(xp + 512);
    float4 x11 = *reinterpret_cast<const float4*>(xp + 512 + 4);

    float l[16];
    float carry = 0.0f;

    #pragma unroll
    for (int t = 0; t < 2; ++t) {
        const float4 wv0 = t ? w10 : w00;
        const float4 wv1 = t ? w11 : w01;
        const float4 xv0 = t ? x10 : x00;
        const float4 xv1 = t ? x11 : x01;
        float p0 = wv0.x * xv0.x, p1 = wv0.y * xv0.y, p2 = wv0.z * xv0.z, p3 = wv0.w * xv0.w;
        float p4 = wv1.x * xv1.x, p5 = wv1.y * xv1.y, p6 = wv1.z * xv1.z, p7 = wv1.w * xv1.w;
        float s8 = ((p0 + p1) + (p2 + p3)) + ((p4 + p5) + (p6 + p7));
        float incl = s8;
        #pragma unroll
        for (int off = 1; off < 64; off <<= 1) {
            float tv = __shfl_up(incl, off, 64);
            incl += (lane >= off) ? tv : 0.0f;
        }
        float a = carry + incl - s8;     // exclusive prefix within quarter
        l[8*t+0] = a; a += p0;
        l[8*t+1] = a; a += p1;
        l[8*t+2] = a; a += p2;
        l[8*t+3] = a; a += p3;
        l[8*t+4] = a; a += p4;
        l[8*t+5] = a; a += p5;
        l[8*t+6] = a; a += p6;
        l[8*t+7] = a;
        carry += __shfl(incl, 63, 64);
    }

    if (lane == 63) qtot[q] = carry;
    __syncthreads();

    float base = c[h];
    if (q >= 1) base += qtot[0];
    if (q >= 2) base += qtot[1];
    if (q >= 3) base += qtot[2];

    __half* sp = S + (size_t)h * D_DIM + col0;
    #pragma unroll
    for (int t = 0; t < 2; ++t) {
        union { __half2 h2[4]; uint4 u; } P;
        #pragma unroll
        for (int j = 0; j < 4; ++j)
            P.h2[j] = __floats2half2_rn(fast_sigmoid(l[8*t+2*j]   + base),
                                        fast_sigmoid(l[8*t+2*j+1] + base));
        *reinterpret_cast<uint4*>(sp + t * 512) = P.u;
    }
}

// ---------------- Kernel B: part[ht][i] = sum_{h in tile} v[i,h]*S[h,i] ----
// R10-exact. grid 2048 (64 i-tiles x 32 h-tiles) x 256 thr, LDS 17 KB.
__global__ __launch_bounds__(256, 8) void nade_vdot_kernel(
    const float* __restrict__ v,
    const __half* __restrict__ S,
    float* __restrict__ part)
{
    __shared__ __half Sl[128][64];   // 16 KB
    __shared__ float red[4][64];

    const int tid = threadIdx.x;
    const int it  = blockIdx.x & 63;
    const int ht  = blockIdx.x >> 6;
    const int i0  = it * 64;
    const int h0  = ht * 128;

    // stage S tile: 128 rows x 128B
    {
        const int r  = tid >> 3;       // 32 rows per pass
        const int c8 = tid & 7;        // 16B chunk in row
        #pragma unroll
        for (int p = 0; p < 4; ++p) {
            const int hh = p * 32 + r;
            uint4 d = *reinterpret_cast<const uint4*>(
                S + (size_t)(h0 + hh) * D_DIM + i0 + c8 * 8);
            *reinterpret_cast<uint4*>(&Sl[hh][c8 * 8]) = d;
        }
    }
    __syncthreads();

    const int il = tid & 63;           // i within tile
    const int q  = tid >> 6;           // wave = 32-h subrange
    const float* vp = v + (size_t)(i0 + il) * H_DIM + h0 + q * 32;

    float4 va[8];
    #pragma unroll
    for (int k = 0; k < 8; ++k)
        va[k] = *reinterpret_cast<const float4*>(vp + 4 * k);

    float acc = 0.0f;
    #pragma unroll
    for (int k = 0; k < 8; ++k) {
        const int hb = q * 32 + 4 * k;
        acc += va[k].x * __half2float(Sl[hb + 0][il])
             + va[k].y * __half2float(Sl[hb + 1][il])
             + va[k].z * __half2float(Sl[hb + 2][il])
             + va[k].w * __half2float(Sl[hb + 3][il]);
    }
    red[q][il] = acc;
    __syncthreads();
    if (q == 0)
        part[(size_t)ht * D_DIM + i0 + il] =
            red[0][il] + red[1][il] + red[2][il] + red[3][il];
}

// ---------------- Kernel C: out = sigmoid(b + sum_32 part) ----------------
__global__ __launch_bounds__(256, 8) void nade_out_kernel(
    const float* __restrict__ part,
    const float* __restrict__ b,
    float* __restrict__ out)
{
    const int i = blockIdx.x * 256 + threadIdx.x;
    float t = b[i];
    #pragma unroll
    for (int s = 0; s < 32; ++s)
        t += part[(size_t)s * D_DIM + i];
    out[i] = fast_sigmoid(t);
}

// ---------------- Fallback (ws too small): fused atomic ----------------
__global__ __launch_bounds__(1024, 1) void nade_fused_atomic(
    const float* __restrict__ x,
    const float* __restrict__ w,
    const float* __restrict__ v,
    const float* __restrict__ c,
    float* __restrict__ logits)
{
    __shared__ __half S[16][D_DIM];   // 128 KB

    const int tid  = threadIdx.x;
    const int wv   = tid >> 6;
    const int lane = tid & 63;
    const int h0   = blockIdx.x * 16;

    const float* wrow = w + (size_t)(h0 + wv) * D_DIM + 8 * lane;
    float carry = c[h0 + wv];
    #pragma unroll
    for (int t = 0; t < 8; ++t) {
        float4 w0 = *reinterpret_cast<const float4*>(wrow + t * 512);
        float4 w1 = *reinterpret_cast<const float4*>(wrow + t * 512 + 4);
        float4 x0 = *reinterpret_cast<const float4*>(x + t * 512 + 8 * lane);
        float4 x1 = *reinterpret_cast<const float4*>(x + t * 512 + 8 * lane + 4);
        float p0 = w0.x * x0.x, p1 = w0.y * x0.y, p2 = w0.z * x0.z, p3 = w0.w * x0.w;
        float p4 = w1.x * x1.x, p5 = w1.y * x1.y, p6 = w1.z * x1.z, p7 = w1.w * x1.w;
        float s8 = ((p0 + p1) + (p2 + p3)) + ((p4 + p5) + (p6 + p7));
        float incl = s8;
        #pragma unroll
        for (int off = 1; off < 64; off <<= 1) {
            float tv = __shfl_up(incl, off, 64);
            incl += (lane >= off) ? tv : 0.0f;
        }
        float tot = __shfl(incl, 63, 64);
        float a = carry + incl - s8;
        float sg0 = fast_sigmoid(a); a += p0;
        float sg1 = fast_sigmoid(a); a += p1;
        float sg2 = fast_sigmoid(a); a += p2;
        float sg3 = fast_sigmoid(a); a += p3;
        float sg4 = fast_sigmoid(a); a += p4;
        float sg5 = fast_sigmoid(a); a += p5;
        float sg6 = fast_sigmoid(a); a += p6;
        float sg7 = fast_sigmoid(a);
        carry += tot;
        union { __half2 h2[4]; uint4 u; } P;
        P.h2[0] = __floats2half2_rn(sg0, sg1);
        P.h2[1] = __floats2half2_rn(sg2, sg3);
        P.h2[2] = __floats2half2_rn(sg4, sg5);
        P.h2[3] = __floats2half2_rn(sg6, sg7);
        *reinterpret_cast<uint4*>(&S[wv][t * 512 + 8 * lane]) = P.u;
    }
    __syncthreads();

    const int i0 = 4 * tid;
    float acc[4] = {0.f, 0.f, 0.f, 0.f};
    #pragma unroll
    for (int r = 0; r < 4; ++r) {
        const float* vp = v + (size_t)(i0 + r) * H_DIM + h0;
        float4 q0 = *reinterpret_cast<const float4*>(vp);
        float4 q1 = *reinterpret_cast<const float4*>(vp + 4);
        float4 q2 = *reinterpret_cast<const float4*>(vp + 8);
        float4 q3 = *reinterpret_cast<const float4*>(vp + 12);
        acc[r] = q0.x * __half2float(S[0][i0 + r])  + q0.y * __half2float(S[1][i0 + r])
               + q0.z * __half2float(S[2][i0 + r])  + q0.w * __half2float(S[3][i0 + r])
               + q1.x * __half2float(S[4][i0 + r])  + q1.y * __half2float(S[5][i0 + r])
               + q1.z * __half2float(S[6][i0 + r])  + q1.w * __half2float(S[7][i0 + r])
               + q2.x * __half2float(S[8][i0 + r])  + q2.y * __half2float(S[9][i0 + r])
               + q2.z * __half2float(S[10][i0 + r]) + q2.w * __half2float(S[11][i0 + r])
               + q3.x * __half2float(S[12][i0 + r]) + q3.y * __half2float(S[13][i0 + r])
               + q3.z * __half2float(S[14][i0 + r]) + q3.w * __half2float(S[15][i0 + r]);
    }
    #pragma unroll
    for (int r = 0; r < 4; ++r) atomicAdd(&logits[i0 + r], acc[r]);
}

__global__ __launch_bounds__(256, 1) void nade_final_atomic(
    const float* __restrict__ logits,
    const float* __restrict__ b,
    float* __restrict__ out)
{
    const int i = blockIdx.x * 256 + threadIdx.x;
    out[i] = fast_sigmoid(logits[i] + b[i]);
}

extern "C" void kernel_launch(void* const* d_in, const int* in_sizes, int n_in,
                              void* d_out, int out_size, void* d_ws, size_t ws_size,
                              hipStream_t stream)
{
    const float* x = (const float*)d_in[0];
    const float* w = (const float*)d_in[1];
    const float* b = (const float*)d_in[2];
    const float* v = (const float*)d_in[3];
    const float* c = (const float*)d_in[4];
    float* out = (float*)d_out;

    const size_t s_bytes    = (size_t)H_DIM * D_DIM * sizeof(__half);   // 32 MB
    const size_t part_bytes = (size_t)32 * D_DIM * sizeof(float);       // 512 KB

    if (ws_size >= s_bytes + part_bytes) {
        __half* S    = (__half*)d_ws;
        float*  part = (float*)((char*)d_ws + s_bytes);
        nade_scan_kernel<<<H_DIM, 256, 0, stream>>>(x, w, c, S);
        nade_vdot_kernel<<<64 * 32, 256, 0, stream>>>(v, S, part);
        nade_out_kernel<<<D_DIM / 256, 256, 0, stream>>>(part, b, out);
    } else {
        float* logits = (float*)d_ws;
        hipMemsetAsync(logits, 0, D_DIM * sizeof(float), stream);
        nade_fused_atomic<<<H_DIM / 16, 1024, 0, stream>>>(x, w, v, c, logits);
        nade_final_atomic<<<D_DIM / 256, 256, 0, stream>>>(logits, b, out);
    }
}

// Round 14
// 43.731 us; speedup vs baseline: 1.2063x; 1.0208x over previous
//
#include <hip/hip_runtime.h>
#include <hip/hip_fp16.h>

#define D_DIM 4096
#define H_DIM 4096

__device__ __forceinline__ float fast_sigmoid(float a) {
    return __builtin_amdgcn_rcpf(1.0f + __expf(-a));
}

// ---------------- Kernel A: quarter-split row scans -> S fp16 (R13-exact) ---
__global__ __launch_bounds__(256, 8) void nade_scan_kernel(
    const float* __restrict__ x,
    const float* __restrict__ w,
    const float* __restrict__ c,
    __half* __restrict__ S)
{
    __shared__ float qtot[4];

    const int tid  = threadIdx.x;
    const int q    = tid >> 6;          // quarter 0..3
    const int lane = tid & 63;
    const int h    = blockIdx.x;
    const int col0 = q * 1024 + 8 * lane;

    const float* wp = w + (size_t)h * D_DIM + col0;
    const float* xp = x + col0;

    float4 w00 = *reinterpret_cast<const float4*>(wp);
    float4 w01 = *reinterpret_cast<const float4*>(wp + 4);
    float4 w10 = *reinterpret_cast<const float4*>(wp + 512);
    float4 w11 = *reinterpret_cast<const float4*>(wp + 512 + 4);
    float4 x00 = *reinterpret_cast<const float4*>(xp);
    float4 x01 = *reinterpret_cast<const float4*>(xp + 4);
    float4 x10 = *reinterpret_cast<const float4*>(xp + 512);
    float4 x11 = *reinterpret_cast<const float4*>(xp + 512 + 4);

    float l[16];
    float carry = 0.0f;

    #pragma unroll
    for (int t = 0; t < 2; ++t) {
        const float4 wv0 = t ? w10 : w00;
        const float4 wv1 = t ? w11 : w01;
        const float4 xv0 = t ? x10 : x00;
        const float4 xv1 = t ? x11 : x01;
        float p0 = wv0.x * xv0.x, p1 = wv0.y * xv0.y, p2 = wv0.z * xv0.z, p3 = wv0.w * xv0.w;
        float p4 = wv1.x * xv1.x, p5 = wv1.y * xv1.y, p6 = wv1.z * xv1.z, p7 = wv1.w * xv1.w;
        float s8 = ((p0 + p1) + (p2 + p3)) + ((p4 + p5) + (p6 + p7));
        float incl = s8;
        #pragma unroll
        for (int off = 1; off < 64; off <<= 1) {
            float tv = __shfl_up(incl, off, 64);
            incl += (lane >= off) ? tv : 0.0f;
        }
        float a = carry + incl - s8;     // exclusive prefix within quarter
        l[8*t+0] = a; a += p0;
        l[8*t+1] = a; a += p1;
        l[8*t+2] = a; a += p2;
        l[8*t+3] = a; a += p3;
        l[8*t+4] = a; a += p4;
        l[8*t+5] = a; a += p5;
        l[8*t+6] = a; a += p6;
        l[8*t+7] = a;
        carry += __shfl(incl, 63, 64);
    }

    if (lane == 63) qtot[q] = carry;
    __syncthreads();

    float base = c[h];
    if (q >= 1) base += qtot[0];
    if (q >= 2) base += qtot[1];
    if (q >= 3) base += qtot[2];

    __half* sp = S + (size_t)h * D_DIM + col0;
    #pragma unroll
    for (int t = 0; t < 2; ++t) {
        union { __half2 h2[4]; uint4 u; } P;
        #pragma unroll
        for (int j = 0; j < 4; ++j)
            P.h2[j] = __floats2half2_rn(fast_sigmoid(l[8*t+2*j]   + base),
                                        fast_sigmoid(l[8*t+2*j+1] + base));
        *reinterpret_cast<uint4*>(sp + t * 512) = P.u;
    }
}

// ---------------- Kernel B: wave-contiguous v + swizzled-LDS S columns -----
// grid 2048 (64 i-tiles x 32 h-tiles) x 256 thr (4 waves), 8 blocks/CU.
// v read: lanes 0-31 = one i-row's 512B (float4 along h), lanes 32-63 = next
// row; 8 row-pair loads pre-issued -> sequential lines, coalescer-friendly.
// S tile in LDS with chunk-XOR swizzle (chunk ^= (h>>2)&7) so the per-lane
// column reads spread over 8 banks (<=4-way). Same involution on write+read.
// Per-i dot reduced with 5 shfl_xor within each 32-lane half.
__global__ __launch_bounds__(256, 8) void nade_vdot_kernel(
    const float* __restrict__ v,
    const __half* __restrict__ S,
    float* __restrict__ part)
{
    __shared__ __half Sl[128 * 64];   // 16 KB, swizzled

    const int tid  = threadIdx.x;
    const int it   = blockIdx.x & 63;
    const int ht   = blockIdx.x >> 6;
    const int i0   = it * 64;
    const int h0   = ht * 128;
    const int lane = tid & 63;
    const int wv   = tid >> 6;

    // stage S tile: logical (hh, chunk c8) -> phys chunk c8 ^ ((hh>>2)&7)
    {
        const int r  = tid >> 3;       // 32 rows per pass
        const int c8 = tid & 7;        // 16B chunk (8 halves)
        #pragma unroll
        for (int p = 0; p < 4; ++p) {
            const int hh = p * 32 + r;
            uint4 d = *reinterpret_cast<const uint4*>(
                S + (size_t)(h0 + hh) * D_DIM + i0 + c8 * 8);
            *reinterpret_cast<uint4*>(
                &Sl[hh * 64 + ((c8 ^ ((hh >> 2) & 7)) << 3)]) = d;
        }
    }

    // pre-issue all 8 v row-pair loads (each: 2 x 512B contiguous segments)
    const int hl  = (lane & 31) * 4;        // lane's h-offset within tile
    const int rwb = wv * 16 + (lane >> 5);  // row base: low half +0, high half +1
    float4 vr[8];
    #pragma unroll
    for (int j = 0; j < 8; ++j) {
        const int row = rwb + 2 * j;
        vr[j] = *reinterpret_cast<const float4*>(
            v + (size_t)(i0 + row) * H_DIM + h0 + hl);
    }

    __syncthreads();

    auto sget = [&](int h_loc, int i) -> float {
        return __half2float(
            Sl[h_loc * 64 + ((((i) >> 3) ^ ((h_loc >> 2) & 7)) << 3) + (i & 7)]);
    };

    #pragma unroll
    for (int j = 0; j < 8; ++j) {
        const int row = rwb + 2 * j;
        float acc = vr[j].x * sget(hl + 0, row)
                  + vr[j].y * sget(hl + 1, row)
                  + vr[j].z * sget(hl + 2, row)
                  + vr[j].w * sget(hl + 3, row);
        #pragma unroll
        for (int mask = 1; mask <= 16; mask <<= 1)
            acc += __shfl_xor(acc, mask, 64);
        if ((lane & 31) == 0)
            part[(size_t)ht * D_DIM + i0 + row] = acc;
    }
}

// ---------------- Kernel C: out = sigmoid(b + sum_32 part) ----------------
__global__ __launch_bounds__(256, 8) void nade_out_kernel(
    const float* __restrict__ part,
    const float* __restrict__ b,
    float* __restrict__ out)
{
    const int i = blockIdx.x * 256 + threadIdx.x;
    float t = b[i];
    #pragma unroll
    for (int s = 0; s < 32; ++s)
        t += part[(size_t)s * D_DIM + i];
    out[i] = fast_sigmoid(t);
}

// ---------------- Fallback (ws too small): fused atomic ----------------
__global__ __launch_bounds__(1024, 1) void nade_fused_atomic(
    const float* __restrict__ x,
    const float* __restrict__ w,
    const float* __restrict__ v,
    const float* __restrict__ c,
    float* __restrict__ logits)
{
    __shared__ __half S[16][D_DIM];   // 128 KB

    const int tid  = threadIdx.x;
    const int wv   = tid >> 6;
    const int lane = tid & 63;
    const int h0   = blockIdx.x * 16;

    const float* wrow = w + (size_t)(h0 + wv) * D_DIM + 8 * lane;
    float carry = c[h0 + wv];
    #pragma unroll
    for (int t = 0; t < 8; ++t) {
        float4 w0 = *reinterpret_cast<const float4*>(wrow + t * 512);
        float4 w1 = *reinterpret_cast<const float4*>(wrow + t * 512 + 4);
        float4 x0 = *reinterpret_cast<const float4*>(x + t * 512 + 8 * lane);
        float4 x1 = *reinterpret_cast<const float4*>(x + t * 512 + 8 * lane + 4);
        float p0 = w0.x * x0.x, p1 = w0.y * x0.y, p2 = w0.z * x0.z, p3 = w0.w * x0.w;
        float p4 = w1.x * x1.x, p5 = w1.y * x1.y, p6 = w1.z * x1.z, p7 = w1.w * x1.w;
        float s8 = ((p0 + p1) + (p2 + p3)) + ((p4 + p5) + (p6 + p7));
        float incl = s8;
        #pragma unroll
        for (int off = 1; off < 64; off <<= 1) {
            float tv = __shfl_up(incl, off, 64);
            incl += (lane >= off) ? tv : 0.0f;
        }
        float tot = __shfl(incl, 63, 64);
        float a = carry + incl - s8;
        float sg0 = fast_sigmoid(a); a += p0;
        float sg1 = fast_sigmoid(a); a += p1;
        float sg2 = fast_sigmoid(a); a += p2;
        float sg3 = fast_sigmoid(a); a += p3;
        float sg4 = fast_sigmoid(a); a += p4;
        float sg5 = fast_sigmoid(a); a += p5;
        float sg6 = fast_sigmoid(a); a += p6;
        float sg7 = fast_sigmoid(a);
        carry += tot;
        union { __half2 h2[4]; uint4 u; } P;
        P.h2[0] = __floats2half2_rn(sg0, sg1);
        P.h2[1] = __floats2half2_rn(sg2, sg3);
        P.h2[2] = __floats2half2_rn(sg4, sg5);
        P.h2[3] = __floats2half2_rn(sg6, sg7);
        *reinterpret_cast<uint4*>(&S[wv][t * 512 + 8 * lane]) = P.u;
    }
    __syncthreads();

    const int i0 = 4 * tid;
    float acc[4] = {0.f, 0.f, 0.f, 0.f};
    #pragma unroll
    for (int r = 0; r < 4; ++r) {
        const float* vp = v + (size_t)(i0 + r) * H_DIM + h0;
        float4 q0 = *reinterpret_cast<const float4*>(vp);
        float4 q1 = *reinterpret_cast<const float4*>(vp + 4);
        float4 q2 = *reinterpret_cast<const float4*>(vp + 8);
        float4 q3 = *reinterpret_cast<const float4*>(vp + 12);
        acc[r] = q0.x * __half2float(S[0][i0 + r])  + q0.y * __half2float(S[1][i0 + r])
               + q0.z * __half2float(S[2][i0 + r])  + q0.w * __half2float(S[3][i0 + r])
               + q1.x * __half2float(S[4][i0 + r])  + q1.y * __half2float(S[5][i0 + r])
               + q1.z * __half2float(S[6][i0 + r])  + q1.w * __half2float(S[7][i0 + r])
               + q2.x * __half2float(S[8][i0 + r])  + q2.y * __half2float(S[9][i0 + r])
               + q2.z * __half2float(S[10][i0 + r]) + q2.w * __half2float(S[11][i0 + r])
               + q3.x * __half2float(S[12][i0 + r]) + q3.y * __half2float(S[13][i0 + r])
               + q3.z * __half2float(S[14][i0 + r]) + q3.w * __half2float(S[15][i0 + r]);
    }
    #pragma unroll
    for (int r = 0; r < 4; ++r) atomicAdd(&logits[i0 + r], acc[r]);
}

__global__ __launch_bounds__(256, 1) void nade_final_atomic(
    const float* __restrict__ logits,
    const float* __restrict__ b,
    float* __restrict__ out)
{
    const int i = blockIdx.x * 256 + threadIdx.x;
    out[i] = fast_sigmoid(logits[i] + b[i]);
}

extern "C" void kernel_launch(void* const* d_in, const int* in_sizes, int n_in,
                              void* d_out, int out_size, void* d_ws, size_t ws_size,
                              hipStream_t stream)
{
    const float* x = (const float*)d_in[0];
    const float* w = (const float*)d_in[1];
    const float* b = (const float*)d_in[2];
    const float* v = (const float*)d_in[3];
    const float* c = (const float*)d_in[4];
    float* out = (float*)d_out;

    const size_t s_bytes    = (size_t)H_DIM * D_DIM * sizeof(__half);   // 32 MB
    const size_t part_bytes = (size_t)32 * D_DIM * sizeof(float);       // 512 KB

    if (ws_size >= s_bytes + part_bytes) {
        __half* S    = (__half*)d_ws;
        float*  part = (float*)((char*)d_ws + s_bytes);
        nade_scan_kernel<<<H_DIM, 256, 0, stream>>>(x, w, c, S);
        nade_vdot_kernel<<<64 * 32, 256, 0, stream>>>(v, S, part);
        nade_out_kernel<<<D_DIM / 256, 256, 0, stream>>>(part, b, out);
    } else {
        float* logits = (float*)d_ws;
        hipMemsetAsync(logits, 0, D_DIM * sizeof(float), stream);
        nade_fused_atomic<<<H_DIM / 16, 1024, 0, stream>>>(x, w, v, c, logits);
        nade_final_atomic<<<D_DIM / 256, 256, 0, stream>>>(logits, b, out);
    }
}

// Round 15
// 40.588 us; speedup vs baseline: 1.2997x; 1.0774x over previous
//
#include <hip/hip_runtime.h>
#include <hip/hip_fp16.h>
#include <stdint.h>

#define D_DIM 4096
#define H_DIM 4096

__device__ __forceinline__ float fast_sigmoid(float a) {
    return __builtin_amdgcn_rcpf(1.0f + __expf(-a));
}

// ---------------- Kernel A: quarter-split row scans -> S uint8 --------------
// grid 4096 x 256 thr (4 waves); wave q owns cols [q*1024, q*1024+1024).
// Same structure as R13; sigmoids quantized to uint8 (q = rn(sigma*255)),
// packed 8/thread -> uint2 store (512B per wave instruction).
__global__ __launch_bounds__(256, 8) void nade_scan_kernel(
    const float* __restrict__ x,
    const float* __restrict__ w,
    const float* __restrict__ c,
    uint8_t* __restrict__ S8)
{
    __shared__ float qtot[4];

    const int tid  = threadIdx.x;
    const int q    = tid >> 6;          // quarter 0..3
    const int lane = tid & 63;
    const int h    = blockIdx.x;
    const int col0 = q * 1024 + 8 * lane;

    const float* wp = w + (size_t)h * D_DIM + col0;
    const float* xp = x + col0;

    float4 w00 = *reinterpret_cast<const float4*>(wp);
    float4 w01 = *reinterpret_cast<const float4*>(wp + 4);
    float4 w10 = *reinterpret_cast<const float4*>(wp + 512);
    float4 w11 = *reinterpret_cast<const float4*>(wp + 512 + 4);
    float4 x00 = *reinterpret_cast<const float4*>(xp);
    float4 x01 = *reinterpret_cast<const float4*>(xp + 4);
    float4 x10 = *reinterpret_cast<const float4*>(xp + 512);
    float4 x11 = *reinterpret_cast<const float4*>(xp + 512 + 4);

    float l[16];
    float carry = 0.0f;

    #pragma unroll
    for (int t = 0; t < 2; ++t) {
        const float4 wv0 = t ? w10 : w00;
        const float4 wv1 = t ? w11 : w01;
        const float4 xv0 = t ? x10 : x00;
        const float4 xv1 = t ? x11 : x01;
        float p0 = wv0.x * xv0.x, p1 = wv0.y * xv0.y, p2 = wv0.z * xv0.z, p3 = wv0.w * xv0.w;
        float p4 = wv1.x * xv1.x, p5 = wv1.y * xv1.y, p6 = wv1.z * xv1.z, p7 = wv1.w * xv1.w;
        float s8 = ((p0 + p1) + (p2 + p3)) + ((p4 + p5) + (p6 + p7));
        float incl = s8;
        #pragma unroll
        for (int off = 1; off < 64; off <<= 1) {
            float tv = __shfl_up(incl, off, 64);
            incl += (lane >= off) ? tv : 0.0f;
        }
        float a = carry + incl - s8;     // exclusive prefix within quarter
        l[8*t+0] = a; a += p0;
        l[8*t+1] = a; a += p1;
        l[8*t+2] = a; a += p2;
        l[8*t+3] = a; a += p3;
        l[8*t+4] = a; a += p4;
        l[8*t+5] = a; a += p5;
        l[8*t+6] = a; a += p6;
        l[8*t+7] = a;
        carry += __shfl(incl, 63, 64);
    }

    if (lane == 63) qtot[q] = carry;
    __syncthreads();

    float base = c[h];
    if (q >= 1) base += qtot[0];
    if (q >= 2) base += qtot[1];
    if (q >= 3) base += qtot[2];

    uint8_t* sp = S8 + (size_t)h * D_DIM + col0;
    #pragma unroll
    for (int t = 0; t < 2; ++t) {
        unsigned qb[8];
        #pragma unroll
        for (int j = 0; j < 8; ++j)
            qb[j] = __float2uint_rn(fast_sigmoid(l[8*t+j] + base) * 255.0f);
        uint2 pk;
        pk.x = qb[0] | (qb[1] << 8) | (qb[2] << 16) | (qb[3] << 24);
        pk.y = qb[4] | (qb[5] << 8) | (qb[6] << 16) | (qb[7] << 24);
        *reinterpret_cast<uint2*>(sp + t * 512) = pk;
    }
}

// ---------------- Kernel B: wave-contiguous v + swizzled uint8 LDS tile ----
// grid 2048 (64 i-tiles x 32 h-tiles) x 256 thr. S tile 128h x 64i bytes =
// 8 KB LDS, chunk-XOR involution (c8 ^ ((hh>>2)&7)) on 8-byte chunks, same
// formula on write and read. v: 8 pre-issued row-pair float4 loads (512B
// contiguous per half-wave). Dot decoded by a single *1/255 at the end.
__global__ __launch_bounds__(256, 8) void nade_vdot_kernel(
    const float* __restrict__ v,
    const uint8_t* __restrict__ S8,
    float* __restrict__ part)
{
    __shared__ uint8_t Sl[128 * 64];   // 8 KB, swizzled

    const int tid  = threadIdx.x;
    const int it   = blockIdx.x & 63;
    const int ht   = blockIdx.x >> 6;
    const int i0   = it * 64;
    const int h0   = ht * 128;
    const int lane = tid & 63;
    const int wv   = tid >> 6;

    // stage S tile: (hh, 8B-chunk c8) -> phys chunk c8 ^ ((hh>>2)&7)
    {
        const int r  = tid >> 3;       // 32 rows per pass
        const int c8 = tid & 7;        // 8B chunk in 64B row
        #pragma unroll
        for (int p = 0; p < 4; ++p) {
            const int hh = p * 32 + r;
            uint2 d = *reinterpret_cast<const uint2*>(
                S8 + (size_t)(h0 + hh) * D_DIM + i0 + c8 * 8);
            *reinterpret_cast<uint2*>(
                &Sl[hh * 64 + ((c8 ^ ((hh >> 2) & 7)) << 3)]) = d;
        }
    }

    // pre-issue all 8 v row-pair loads (each half-wave: 512B contiguous)
    const int hl  = (lane & 31) * 4;        // lane's h-offset within tile
    const int rwb = wv * 16 + (lane >> 5);  // row base
    float4 vr[8];
    #pragma unroll
    for (int j = 0; j < 8; ++j) {
        const int row = rwb + 2 * j;
        vr[j] = *reinterpret_cast<const float4*>(
            v + (size_t)(i0 + row) * H_DIM + h0 + hl);
    }

    __syncthreads();

    auto sget = [&](int h_loc, int i) -> float {
        return (float)Sl[h_loc * 64
                         + ((((i) >> 3) ^ ((h_loc >> 2) & 7)) << 3) + (i & 7)];
    };

    #pragma unroll
    for (int j = 0; j < 8; ++j) {
        const int row = rwb + 2 * j;
        float acc = vr[j].x * sget(hl + 0, row)
                  + vr[j].y * sget(hl + 1, row)
                  + vr[j].z * sget(hl + 2, row)
                  + vr[j].w * sget(hl + 3, row);
        #pragma unroll
        for (int mask = 1; mask <= 16; mask <<= 1)
            acc += __shfl_xor(acc, mask, 64);
        if ((lane & 31) == 0)
            part[(size_t)ht * D_DIM + i0 + row] = acc * (1.0f / 255.0f);
    }
}

// ---------------- Kernel C: out = sigmoid(b + sum_32 part) ----------------
__global__ __launch_bounds__(256, 8) void nade_out_kernel(
    const float* __restrict__ part,
    const float* __restrict__ b,
    float* __restrict__ out)
{
    const int i = blockIdx.x * 256 + threadIdx.x;
    float t = b[i];
    #pragma unroll
    for (int s = 0; s < 32; ++s)
        t += part[(size_t)s * D_DIM + i];
    out[i] = fast_sigmoid(t);
}

// ---------------- Fallback (ws too small): fused atomic (fp16 LDS) --------
__global__ __launch_bounds__(1024, 1) void nade_fused_atomic(
    const float* __restrict__ x,
    const float* __restrict__ w,
    const float* __restrict__ v,
    const float* __restrict__ c,
    float* __restrict__ logits)
{
    __shared__ __half S[16][D_DIM];   // 128 KB

    const int tid  = threadIdx.x;
    const int wv   = tid >> 6;
    const int lane = tid & 63;
    const int h0   = blockIdx.x * 16;

    const float* wrow = w + (size_t)(h0 + wv) * D_DIM + 8 * lane;
    float carry = c[h0 + wv];
    #pragma unroll
    for (int t = 0; t < 8; ++t) {
        float4 w0 = *reinterpret_cast<const float4*>(wrow + t * 512);
        float4 w1 = *reinterpret_cast<const float4*>(wrow + t * 512 + 4);
        float4 x0 = *reinterpret_cast<const float4*>(x + t * 512 + 8 * lane);
        float4 x1 = *reinterpret_cast<const float4*>(x + t * 512 + 8 * lane + 4);
        float p0 = w0.x * x0.x, p1 = w0.y * x0.y, p2 = w0.z * x0.z, p3 = w0.w * x0.w;
        float p4 = w1.x * x1.x, p5 = w1.y * x1.y, p6 = w1.z * x1.z, p7 = w1.w * x1.w;
        float s8 = ((p0 + p1) + (p2 + p3)) + ((p4 + p5) + (p6 + p7));
        float incl = s8;
        #pragma unroll
        for (int off = 1; off < 64; off <<= 1) {
            float tv = __shfl_up(incl, off, 64);
            incl += (lane >= off) ? tv : 0.0f;
        }
        float tot = __shfl(incl, 63, 64);
        float a = carry + incl - s8;
        float sg0 = fast_sigmoid(a); a += p0;
        float sg1 = fast_sigmoid(a); a += p1;
        float sg2 = fast_sigmoid(a); a += p2;
        float sg3 = fast_sigmoid(a); a += p3;
        float sg4 = fast_sigmoid(a); a += p4;
        float sg5 = fast_sigmoid(a); a += p5;
        float sg6 = fast_sigmoid(a); a += p6;
        float sg7 = fast_sigmoid(a);
        carry += tot;
        union { __half2 h2[4]; uint4 u; } P;
        P.h2[0] = __floats2half2_rn(sg0, sg1);
        P.h2[1] = __floats2half2_rn(sg2, sg3);
        P.h2[2] = __floats2half2_rn(sg4, sg5);
        P.h2[3] = __floats2half2_rn(sg6, sg7);
        *reinterpret_cast<uint4*>(&S[wv][t * 512 + 8 * lane]) = P.u;
    }
    __syncthreads();

    const int i0 = 4 * tid;
    float acc[4] = {0.f, 0.f, 0.f, 0.f};
    #pragma unroll
    for (int r = 0; r < 4; ++r) {
        const float* vp = v + (size_t)(i0 + r) * H_DIM + h0;
        float4 q0 = *reinterpret_cast<const float4*>(vp);
        float4 q1 = *reinterpret_cast<const float4*>(vp + 4);
        float4 q2 = *reinterpret_cast<const float4*>(vp + 8);
        float4 q3 = *reinterpret_cast<const float4*>(vp + 12);
        acc[r] = q0.x * __half2float(S[0][i0 + r])  + q0.y * __half2float(S[1][i0 + r])
               + q0.z * __half2float(S[2][i0 + r])  + q0.w * __half2float(S[3][i0 + r])
               + q1.x * __half2float(S[4][i0 + r])  + q1.y * __half2float(S[5][i0 + r])
               + q1.z * __half2float(S[6][i0 + r])  + q1.w * __half2float(S[7][i0 + r])
               + q2.x * __half2float(S[8][i0 + r])  + q2.y * __half2float(S[9][i0 + r])
               + q2.z * __half2float(S[10][i0 + r]) + q2.w * __half2float(S[11][i0 + r])
               + q3.x * __half2float(S[12][i0 + r]) + q3.y * __half2float(S[13][i0 + r])
               + q3.z * __half2float(S[14][i0 + r]) + q3.w * __half2float(S[15][i0 + r]);
    }
    #pragma unroll
    for (int r = 0; r < 4; ++r) atomicAdd(&logits[i0 + r], acc[r]);
}

__global__ __launch_bounds__(256, 1) void nade_final_atomic(
    const float* __restrict__ logits,
    const float* __restrict__ b,
    float* __restrict__ out)
{
    const int i = blockIdx.x * 256 + threadIdx.x;
    out[i] = fast_sigmoid(logits[i] + b[i]);
}

extern "C" void kernel_launch(void* const* d_in, const int* in_sizes, int n_in,
                              void* d_out, int out_size, void* d_ws, size_t ws_size,
                              hipStream_t stream)
{
    const float* x = (const float*)d_in[0];
    const float* w = (const float*)d_in[1];
    const float* b = (const float*)d_in[2];
    const float* v = (const float*)d_in[3];
    const float* c = (const float*)d_in[4];
    float* out = (float*)d_out;

    const size_t s_bytes    = (size_t)H_DIM * D_DIM * sizeof(uint8_t);  // 16 MB
    const size_t part_bytes = (size_t)32 * D_DIM * sizeof(float);       // 512 KB

    if (ws_size >= s_bytes + part_bytes) {
        uint8_t* S8  = (uint8_t*)d_ws;
        float*   part = (float*)((char*)d_ws + s_bytes);
        nade_scan_kernel<<<H_DIM, 256, 0, stream>>>(x, w, c, S8);
        nade_vdot_kernel<<<64 * 32, 256, 0, stream>>>(v, S8, part);
        nade_out_kernel<<<D_DIM / 256, 256, 0, stream>>>(part, b, out);
    } else {
        float* logits = (float*)d_ws;
        hipMemsetAsync(logits, 0, D_DIM * sizeof(float), stream);
        nade_fused_atomic<<<H_DIM / 16, 1024, 0, stream>>>(x, w, v, c, logits);
        nade_final_atomic<<<D_DIM / 256, 256, 0, stream>>>(logits, b, out);
    }
}